// Round 16
// baseline (73.720 us; speedup 1.0000x reference)
//
#include <hip/hip_runtime.h>
#include <hip/hip_bf16.h>

typedef __attribute__((ext_vector_type(8))) short bf16x8;
typedef __attribute__((ext_vector_type(4))) float f32x4;

#define GRU_B 131072
#define BM 32
#define TPB 8                        // row-tiles per persistent block
#define NBLK (GRU_B / (BM * TPB))    // 512 blocks

static __device__ __forceinline__ ushort f2bf(float f) {
  union { float f; unsigned u; } v; v.f = f;
  unsigned r = v.u + 0x7FFFu + ((v.u >> 16) & 1u);   // RNE
  return (ushort)(r >> 16);
}
static __device__ __forceinline__ float bf2f(ushort u) {
  union { unsigned u; float f; } v; v.u = ((unsigned)u) << 16;
  return v.f;
}
static __device__ __forceinline__ unsigned pk2(float a, float b) {
  float2 t; t.x = a; t.y = b;
  __hip_bfloat162 r = __float22bfloat162_rn(t);      // v_cvt_pk_bf16_f32
  union { __hip_bfloat162 b; unsigned u; } cv; cv.b = r;
  return cv.u;
}
static __device__ __forceinline__ float fsig(float x) {
  return __builtin_amdgcn_rcpf(1.0f + __expf(-x));
}
static __device__ __forceinline__ float ftanh(float x) {
  return 1.0f - 2.0f * __builtin_amdgcn_rcpf(1.0f + __expf(2.0f * x));
}
// two-bit XOR swizzle: b128 row reads 2-way (free), b64 row-gathers conflict-free
static __device__ __forceinline__ int swz(int row, int cbyte) {
  return (row * 256 + cbyte) ^ ((row & 7) << 4) ^ ((row & 8) << 2);
}

// Raw barrier: LDS visibility only — NO vmcnt drain, prefetch loads survive.
#define BARRIER() do {                                       \
  asm volatile("s_waitcnt lgkmcnt(0)" ::: "memory");         \
  __builtin_amdgcn_s_barrier();                              \
  asm volatile("" ::: "memory");                             \
} while (0)

// Pack six 128x128 fp32 weight matrices into per-lane MFMA fragment order:
// chunk = ((mat*8 + cb)*4 + kb), 1KB each; within chunk lane*16B holds
// w[kb*32 + (lane>>4)*8 + e][cb*16 + (lane&15)], e=0..7, bf16.
__global__ void wtrans_kernel(const float* __restrict__ wz, const float* __restrict__ uz,
                              const float* __restrict__ wr, const float* __restrict__ ur,
                              const float* __restrict__ wh, const float* __restrict__ uh,
                              ushort* __restrict__ outw) {
  int f = blockIdx.x * 256 + threadIdx.x;          // 0..98303 (coalesced write)
  int mat = f >> 14;
  int rem = f & 16383;
  int chunk = rem >> 9;                            // 0..31
  int lane = (rem >> 3) & 63;
  int e = rem & 7;
  int cb = chunk >> 2, k0b = chunk & 3;
  int n = cb * 16 + (lane & 15);
  int k = k0b * 32 + (lane >> 4) * 8 + e;
  const float* src = (mat == 0) ? wz : (mat == 1) ? uz : (mat == 2) ? wr
                   : (mat == 3) ? ur : (mat == 4) ? wh : uh;
  outw[f] = f2bf(src[k * 128 + n]);
}

#define MFMA __builtin_amdgcn_mfma_f32_16x16x32_bf16

__global__ __launch_bounds__(512, 2) void gru_kernel(
    const float* __restrict__ x, const float* __restrict__ hprev,
    const ushort* __restrict__ wt,
    const float* __restrict__ bz, const float* __restrict__ br,
    const float* __restrict__ bh, float* __restrict__ out) {
  // 64 KB: S0/S1/S2 @ 0/16K/32K (xs +0, hs +8K); RH0/RH1 @ 48K/56K
  __shared__ __align__(16) char smem[65536];

  const int tid = threadIdx.x;
  const int lane = tid & 63;
  const int wid = tid >> 6;          // 8 waves: 16 output cols each
  const int l15 = lane & 15;
  const int q = lane >> 4;
  const int n0 = wid * 16;

  const float4 brv = *(const float4*)(br + n0 + q * 4);
  const float4 bzv = *(const float4*)(bz + n0 + q * 4);
  const float4 bhv = *(const float4*)(bh + n0 + q * 4);
  const f32x4 brv4 = {brv.x, brv.y, brv.z, brv.w};
  const f32x4 bzv4 = {bzv.x, bzv.y, bzv.z, bzv.w};
  const f32x4 bhv4 = {bhv.x, bhv.y, bhv.z, bhv.w};

  const ushort* wlane = wt + (lane << 3);
  auto wfrag = [&](int mat, int kb) -> const bf16x8* {
    return (const bf16x8*)(wlane + ((((mat << 3) + wid) << 2) + kb) * 512);
  };
  auto ldsA = [&](const char* base, int mr, int k0) -> bf16x8 {
    int row = mr * 16 + l15;
    return *(const bf16x8*)(base + swz(row, (k0 + q * 8) * 2));
  };

  const long tile0 = (long)blockIdx.x * TPB;
  const float4* xg = (const float4*)x;
  const float4* hg = (const float4*)hprev;

  const int r0 = tid >> 5, cb0 = (tid & 31) << 3;
  const int bo0 = swz(r0, cb0), bo1 = swz(r0 + 16, cb0);
  const int go0 = swz(l15, (n0 + q * 4) * 2);
  const int go1 = swz(16 + l15, (n0 + q * 4) * 2);

  auto stage = [&](char* S, const float4& a0, const float4& a1,
                   const float4& b0, const float4& b1) {
    uint2 v;
    v.x = pk2(a0.x, a0.y); v.y = pk2(a0.z, a0.w); *(uint2*)(S + bo0) = v;
    v.x = pk2(a1.x, a1.y); v.y = pk2(a1.z, a1.w); *(uint2*)(S + bo1) = v;
    v.x = pk2(b0.x, b0.y); v.y = pk2(b0.z, b0.w); *(uint2*)(S + 8192 + bo0) = v;
    v.x = pk2(b1.x, b1.y); v.y = pk2(b1.z, b1.w); *(uint2*)(S + 8192 + bo1) = v;
  };
  // rh phase: consume accr -> write RH, cache+return hp pack
  auto rhphase = [&](const char* S, char* RH, const f32x4* accr, uint2* hpk) {
#pragma unroll
    for (int mr = 0; mr < 2; ++mr) {
      int go = mr ? go1 : go0;
      uint2 hp4 = *(const uint2*)(S + 8192 + go);
      hpk[mr] = hp4;
      float h0 = bf2f((ushort)(hp4.x & 0xffff)), h1 = bf2f((ushort)(hp4.x >> 16));
      float h2 = bf2f((ushort)(hp4.y & 0xffff)), h3 = bf2f((ushort)(hp4.y >> 16));
      uint2 w;
      w.x = pk2(fsig(accr[mr][0]) * h0, fsig(accr[mr][1]) * h1);
      w.y = pk2(fsig(accr[mr][2]) * h2, fsig(accr[mr][3]) * h3);
      *(uint2*)(RH + go) = w;
    }
  };

  // -------- prologue: stage tiles 0,1; preload px(2); pass1(0); rh(0) --------
  float4 px0, px1, ph0, ph1;
  {
    long toff = tile0 * 1024;
    px0 = xg[toff + tid]; px1 = xg[toff + 512 + tid];
    ph0 = hg[toff + tid]; ph1 = hg[toff + 512 + tid];
    stage(smem, px0, px1, ph0, ph1);
    toff += 1024;
    px0 = xg[toff + tid]; px1 = xg[toff + 512 + tid];
    ph0 = hg[toff + tid]; ph1 = hg[toff + 512 + tid];
    stage(smem + 16384, px0, px1, ph0, ph1);
    if (TPB > 2) {
      toff += 1024;
      px0 = xg[toff + tid]; px1 = xg[toff + 512 + tid];
      ph0 = hg[toff + tid]; ph1 = hg[toff + 512 + tid];
    }
  }
  BARRIER();   // S0,S1 visible

  f32x4 aPz[2], aPh[2];      // tile-t state carried across the barrier
  uint2 hpkP[2];
  {
    // pass1(0) on S0 (weights streamed; plain, not fused)
    f32x4 ar_[2] = {brv4, brv4}, az_[2] = {bzv4, bzv4}, ah_[2] = {bhv4, bhv4};
#pragma unroll
    for (int kb = 0; kb < 4; ++kb) {
      bf16x8 bWz = *wfrag(0, kb), bUz = *wfrag(1, kb);
      bf16x8 bWr = *wfrag(2, kb), bUr = *wfrag(3, kb);
      bf16x8 bWh = *wfrag(4, kb);
#pragma unroll
      for (int mr = 0; mr < 2; ++mr) {
        bf16x8 ax = ldsA(smem, mr, kb * 32);
        bf16x8 ah = ldsA(smem + 8192, mr, kb * 32);
        ar_[mr] = MFMA(bWr, ax, ar_[mr], 0, 0, 0);
        ar_[mr] = MFMA(bUr, ah, ar_[mr], 0, 0, 0);
        az_[mr] = MFMA(bWz, ax, az_[mr], 0, 0, 0);
        az_[mr] = MFMA(bUz, ah, az_[mr], 0, 0, 0);
        ah_[mr] = MFMA(bWh, ax, ah_[mr], 0, 0, 0);
      }
    }
    rhphase(smem, smem + 49152, ar_, hpkP);   // rh(0) -> RH0
    aPz[0] = az_[0]; aPz[1] = az_[1];
    aPh[0] = ah_[0]; aPh[1] = ah_[1];
  }

  for (int t = 0; t < TPB; ++t) {
    BARRIER();   // rh(t) + S(t+1) [+S(t+2) staged last iter] visible
    char* RHcur = smem + 49152 + (t & 1) * 8192;
    const long row0 = (tile0 + t) * BM;

    if (t + 1 < TPB) {
      char* Snx = smem + ((t + 1) % 3) * 16384;
      // ---- fused region: pass2(t) ∥ pass1(t+1) — two independent dep trees
      f32x4 aNr[2] = {brv4, brv4}, aNz[2] = {bzv4, bzv4}, aNh[2] = {bhv4, bhv4};
      __builtin_amdgcn_s_setprio(1);
#pragma unroll
      for (int kb = 0; kb < 4; ++kb) {
        bf16x8 bWz = *wfrag(0, kb), bUz = *wfrag(1, kb);
        bf16x8 bWr = *wfrag(2, kb), bUr = *wfrag(3, kb);
        bf16x8 bWh = *wfrag(4, kb), bUh = *wfrag(5, kb);
#pragma unroll
        for (int mr = 0; mr < 2; ++mr) {
          bf16x8 ax = ldsA(Snx, mr, kb * 32);
          bf16x8 ah = ldsA(Snx + 8192, mr, kb * 32);
          bf16x8 ar = ldsA(RHcur, mr, kb * 32);
          aPh[mr] = MFMA(bUh, ar, aPh[mr], 0, 0, 0);      // pass2(t)
          aNr[mr] = MFMA(bWr, ax, aNr[mr], 0, 0, 0);      // pass1(t+1)
          aNr[mr] = MFMA(bUr, ah, aNr[mr], 0, 0, 0);
          aNz[mr] = MFMA(bWz, ax, aNz[mr], 0, 0, 0);
          aNz[mr] = MFMA(bUz, ah, aNz[mr], 0, 0, 0);
          aNh[mr] = MFMA(bWh, ax, aNh[mr], 0, 0, 0);
        }
      }
      __builtin_amdgcn_s_setprio(0);

      // ---- rh(t+1) -> RH[(t+1)&1]  (before next barrier) ----
      uint2 hpkN[2];
      rhphase(Snx, smem + 49152 + ((t + 1) & 1) * 8192, aNr, hpkN);

      // ---- stage tile t+2 from px regs; reissue px for t+3 ----
      if (t + 2 < TPB) {
        stage(smem + ((t + 2) % 3) * 16384, px0, px1, ph0, ph1);
        if (t + 3 < TPB) {
          long toff = (tile0 + t + 3) * 1024;
          px0 = xg[toff + tid]; px1 = xg[toff + 512 + tid];
          ph0 = hg[toff + tid]; ph1 = hg[toff + 512 + tid];
        }
      }

      // ---- epilogue(t): h_t = hp + z*(hc-hp); one float4 store per mr ----
#pragma unroll
      for (int mr = 0; mr < 2; ++mr) {
        float hpf[4];
        hpf[0] = bf2f((ushort)(hpkP[mr].x & 0xffff));
        hpf[1] = bf2f((ushort)(hpkP[mr].x >> 16));
        hpf[2] = bf2f((ushort)(hpkP[mr].y & 0xffff));
        hpf[3] = bf2f((ushort)(hpkP[mr].y >> 16));
        float4 v;
#pragma unroll
        for (int j = 0; j < 4; ++j) {
          float hc = ftanh(aPh[mr][j]);
          float zv = fsig(aPz[mr][j]);
          ((float*)&v)[j] = hpf[j] + zv * (hc - hpf[j]);
        }
        *(float4*)(out + (row0 + mr * 16 + l15) * 128 + n0 + q * 4) = v;
      }

      // ---- rotate pipeline state ----
      aPz[0] = aNz[0]; aPz[1] = aNz[1];
      aPh[0] = aNh[0]; aPh[1] = aNh[1];
      hpkP[0] = hpkN[0]; hpkP[1] = hpkN[1];
    } else {
      // ---- last tile: pass2 only + epilogue ----
      __builtin_amdgcn_s_setprio(1);
#pragma unroll
      for (int kb = 0; kb < 4; ++kb) {
        bf16x8 bUh = *wfrag(5, kb);
#pragma unroll
        for (int mr = 0; mr < 2; ++mr)
          aPh[mr] = MFMA(bUh, ldsA(RHcur, mr, kb * 32), aPh[mr], 0, 0, 0);
      }
      __builtin_amdgcn_s_setprio(0);
#pragma unroll
      for (int mr = 0; mr < 2; ++mr) {
        float hpf[4];
        hpf[0] = bf2f((ushort)(hpkP[mr].x & 0xffff));
        hpf[1] = bf2f((ushort)(hpkP[mr].x >> 16));
        hpf[2] = bf2f((ushort)(hpkP[mr].y & 0xffff));
        hpf[3] = bf2f((ushort)(hpkP[mr].y >> 16));
        float4 v;
#pragma unroll
        for (int j = 0; j < 4; ++j) {
          float hc = ftanh(aPh[mr][j]);
          float zv = fsig(aPz[mr][j]);
          ((float*)&v)[j] = hpf[j] + zv * (hc - hpf[j]);
        }
        *(float4*)(out + (row0 + mr * 16 + l15) * 128 + n0 + q * 4) = v;
      }
    }
  }
}

extern "C" void kernel_launch(void* const* d_in, const int* in_sizes, int n_in,
                              void* d_out, int out_size, void* d_ws, size_t ws_size,
                              hipStream_t stream) {
  const float* x  = (const float*)d_in[0];
  const float* h  = (const float*)d_in[1];
  const float* Wz = (const float*)d_in[2];
  const float* Uz = (const float*)d_in[3];
  const float* bz = (const float*)d_in[4];
  const float* Wr = (const float*)d_in[5];
  const float* Ur = (const float*)d_in[6];
  const float* br = (const float*)d_in[7];
  const float* Wh = (const float*)d_in[8];
  const float* Uh = (const float*)d_in[9];
  const float* bh = (const float*)d_in[10];
  ushort* wt = (ushort*)d_ws;   // 98304 bf16 = 192 KB packed fragment order

  hipLaunchKernelGGL(wtrans_kernel, dim3(384), dim3(256), 0, stream,
                     Wz, Uz, Wr, Ur, Wh, Uh, wt);
  hipLaunchKernelGGL(gru_kernel, dim3(NBLK), dim3(512), 0, stream,
                     x, h, wt, bz, br, bh, (float*)d_out);
}

// Round 18
// 59.212 us; speedup vs baseline: 1.2450x; 1.2450x over previous
//
#include <hip/hip_runtime.h>
#include <hip/hip_bf16.h>

typedef __attribute__((ext_vector_type(8))) short bf16x8;
typedef __attribute__((ext_vector_type(4))) float f32x4;

#define GRU_B 131072
#define BM 32
#define TPB 8                        // row-tiles per persistent block
#define NBLK (GRU_B / (BM * TPB))    // 512 blocks

static __device__ __forceinline__ ushort f2bf(float f) {
  union { float f; unsigned u; } v; v.f = f;
  unsigned r = v.u + 0x7FFFu + ((v.u >> 16) & 1u);   // RNE
  return (ushort)(r >> 16);
}
static __device__ __forceinline__ float bf2f(ushort u) {
  union { unsigned u; float f; } v; v.u = ((unsigned)u) << 16;
  return v.f;
}
static __device__ __forceinline__ unsigned pk2(float a, float b) {
  float2 t; t.x = a; t.y = b;
  __hip_bfloat162 r = __float22bfloat162_rn(t);      // v_cvt_pk_bf16_f32
  union { __hip_bfloat162 b; unsigned u; } cv; cv.b = r;
  return cv.u;
}
static __device__ __forceinline__ float fsig(float x) {
  return __builtin_amdgcn_rcpf(1.0f + __expf(-x));
}
static __device__ __forceinline__ float ftanh(float x) {
  return 1.0f - 2.0f * __builtin_amdgcn_rcpf(1.0f + __expf(2.0f * x));
}
// two-bit XOR swizzle: b128 row reads 2-way (free), b64 row-gathers conflict-free
static __device__ __forceinline__ int swz(int row, int cbyte) {
  return (row * 256 + cbyte) ^ ((row & 7) << 4) ^ ((row & 8) << 2);
}

// Raw barrier: LDS visibility only — NO vmcnt drain, prefetch loads survive.
#define BARRIER() do {                                       \
  asm volatile("s_waitcnt lgkmcnt(0)" ::: "memory");         \
  __builtin_amdgcn_s_barrier();                              \
  asm volatile("" ::: "memory");                             \
} while (0)

// Pack six 128x128 fp32 weight matrices into per-lane MFMA fragment order:
// chunk = ((mat*8 + cb)*4 + kb), 1KB each; within chunk lane*16B holds
// w[kb*32 + (lane>>4)*8 + e][cb*16 + (lane&15)], e=0..7, bf16.
// Simultaneously a B-frag of W and an A-frag of W^T (lane-symmetric).
__global__ void wtrans_kernel(const float* __restrict__ wz, const float* __restrict__ uz,
                              const float* __restrict__ wr, const float* __restrict__ ur,
                              const float* __restrict__ wh, const float* __restrict__ uh,
                              ushort* __restrict__ outw) {
  int f = blockIdx.x * 256 + threadIdx.x;          // 0..98303 (coalesced write)
  int mat = f >> 14;
  int rem = f & 16383;
  int chunk = rem >> 9;                            // 0..31
  int lane = (rem >> 3) & 63;
  int e = rem & 7;
  int cb = chunk >> 2, k0b = chunk & 3;
  int n = cb * 16 + (lane & 15);
  int k = k0b * 32 + (lane >> 4) * 8 + e;
  const float* src = (mat == 0) ? wz : (mat == 1) ? uz : (mat == 2) ? wr
                   : (mat == 3) ? ur : (mat == 4) ? wh : uh;
  outw[f] = f2bf(src[k * 128 + n]);
}

#define MFMA __builtin_amdgcn_mfma_f32_16x16x32_bf16

__global__ __launch_bounds__(512, 2) void gru_kernel(
    const float* __restrict__ x, const float* __restrict__ hprev,
    const ushort* __restrict__ wt,
    const float* __restrict__ bz, const float* __restrict__ br,
    const float* __restrict__ bh, float* __restrict__ out) {
  // 64 KB: S[i]=i*16K (xs +0, hs +8K) tri-buffered; RH[r]=48K + r*8K dbuf
  __shared__ __align__(16) char smem[65536];

  const int tid = threadIdx.x;
  const int lane = tid & 63;
  const int wid = tid >> 6;          // 8 waves: 16 output cols each
  const int l15 = lane & 15;
  const int q = lane >> 4;
  const int n0 = wid * 16;

  // SWAPPED output layout: lane holds (batch row m = mtile*16+l15,
  // hidden cols n = n0 + q*4 + j, j=0..3). Bias varies along j:
  const float4 brv = *(const float4*)(br + n0 + q * 4);
  const float4 bzv = *(const float4*)(bz + n0 + q * 4);
  const float4 bhv = *(const float4*)(bh + n0 + q * 4);
  const f32x4 brv4 = {brv.x, brv.y, brv.z, brv.w};
  const f32x4 bzv4 = {bzv.x, bzv.y, bzv.z, bzv.w};
  const f32x4 bhv4 = {bhv.x, bhv.y, bhv.z, bhv.w};

  // hoist all 24 weight fragments into registers (reused across 8 tiles)
  const ushort* wlane = wt + (lane << 3);
  bf16x8 W[6][4];
#pragma unroll
  for (int mat = 0; mat < 6; ++mat)
#pragma unroll
    for (int kb = 0; kb < 4; ++kb)
      W[mat][kb] = *(const bf16x8*)(wlane + ((((mat << 3) + wid) << 2) + kb) * 512);

  auto ldsA = [&](const char* base, int mr, int k0) -> bf16x8 {
    int row = mr * 16 + l15;
    return *(const bf16x8*)(base + swz(row, (k0 + q * 8) * 2));
  };

  const long tile0 = (long)blockIdx.x * TPB;
  const f32x4* xg = (const f32x4*)x;
  const f32x4* hg = (const f32x4*)hprev;

  // staging offsets (lane-constant)
  const int r0 = tid >> 5, cb0 = (tid & 31) << 3;
  const int bo0 = swz(r0, cb0), bo1 = swz(r0 + 16, cb0);
  // rh/hp wide-op offsets: row = mr*16 + l15, byte col = (n0 + q*4)*2
  const int go0 = swz(l15, (n0 + q * 4) * 2);
  const int go1 = swz(16 + l15, (n0 + q * 4) * 2);

  auto stage = [&](char* S, const f32x4& a0, const f32x4& a1,
                   const f32x4& b0, const f32x4& b1) {
    uint2 v;
    v.x = pk2(a0.x, a0.y); v.y = pk2(a0.z, a0.w); *(uint2*)(S + bo0) = v;
    v.x = pk2(a1.x, a1.y); v.y = pk2(a1.z, a1.w); *(uint2*)(S + bo1) = v;
    v.x = pk2(b0.x, b0.y); v.y = pk2(b0.z, b0.w); *(uint2*)(S + 8192 + bo0) = v;
    v.x = pk2(b1.x, b1.y); v.y = pk2(b1.z, b1.w); *(uint2*)(S + 8192 + bo1) = v;
  };

  // -------- prologue: stage tile0, load tile1 regs (nontemporal: pure
  //          streaming data — keep it out of L2 so weight frags stay hot) ----
  f32x4 px0, px1, ph0, ph1;
  {
    long toff = tile0 * 1024;       // f32x4 index of tile 0
    px0 = __builtin_nontemporal_load(xg + toff + tid);
    px1 = __builtin_nontemporal_load(xg + toff + 512 + tid);
    ph0 = __builtin_nontemporal_load(hg + toff + tid);
    ph1 = __builtin_nontemporal_load(hg + toff + 512 + tid);
    stage(smem, px0, px1, ph0, ph1);
    if (TPB > 1) {
      toff += 1024;
      px0 = __builtin_nontemporal_load(xg + toff + tid);
      px1 = __builtin_nontemporal_load(xg + toff + 512 + tid);
      ph0 = __builtin_nontemporal_load(hg + toff + tid);
      ph1 = __builtin_nontemporal_load(hg + toff + 512 + tid);
    }
  }
  BARRIER();

  for (int t = 0; t < TPB; ++t) {
    char* Scur = smem + (t % 3) * 16384;
    char* RHc  = smem + 49152 + (t & 1) * 8192;
    const long row0 = (tile0 + t) * BM;

    // ---- stage tile t+1 from regs ----
    if (t + 1 < TPB) stage(smem + ((t + 1) % 3) * 16384, px0, px1, ph0, ph1);

    // ---- issue tile t+2 loads (raw barrier below won't drain them) ----
    if (t + 2 < TPB) {
      long toff = (tile0 + t + 2) * 1024;
      px0 = __builtin_nontemporal_load(xg + toff + tid);
      px1 = __builtin_nontemporal_load(xg + toff + 512 + tid);
      ph0 = __builtin_nontemporal_load(hg + toff + tid);
      ph1 = __builtin_nontemporal_load(hg + toff + 512 + tid);
    }

    // ---- pass 1 SWAPPED: accT = W^T-frag x act-frag (C^T layout out) ----
    //      accr = (x@Wr + h@Ur + br)^T ; accz ; acch = (x@Wh + bh)^T
    f32x4 accr[2], accz[2], acch[2];
    accr[0] = brv4; accr[1] = brv4;
    accz[0] = bzv4; accz[1] = bzv4;
    acch[0] = bhv4; acch[1] = bhv4;
    __builtin_amdgcn_s_setprio(1);
#pragma unroll
    for (int kb = 0; kb < 4; ++kb)
#pragma unroll
      for (int mr = 0; mr < 2; ++mr) {
        bf16x8 ax = ldsA(Scur, mr, kb * 32);
        bf16x8 ah = ldsA(Scur + 8192, mr, kb * 32);
        accr[mr] = MFMA(W[2][kb], ax, accr[mr], 0, 0, 0);
        accr[mr] = MFMA(W[3][kb], ah, accr[mr], 0, 0, 0);
        accz[mr] = MFMA(W[0][kb], ax, accz[mr], 0, 0, 0);
        accz[mr] = MFMA(W[1][kb], ah, accz[mr], 0, 0, 0);
        acch[mr] = MFMA(W[4][kb], ax, acch[mr], 0, 0, 0);
      }
    __builtin_amdgcn_s_setprio(0);

    // ---- rh = sigmoid(accr)*hp -> RH, WIDE ops (b64), hp cached ----
    uint2 hpk[2];
#pragma unroll
    for (int mr = 0; mr < 2; ++mr) {
      int go = mr ? go1 : go0;
      uint2 hp4 = *(const uint2*)(Scur + 8192 + go);   // 4 bf16 hp
      hpk[mr] = hp4;
      float h0 = bf2f((ushort)(hp4.x & 0xffff)), h1 = bf2f((ushort)(hp4.x >> 16));
      float h2 = bf2f((ushort)(hp4.y & 0xffff)), h3 = bf2f((ushort)(hp4.y >> 16));
      uint2 w;
      w.x = pk2(fsig(accr[mr][0]) * h0, fsig(accr[mr][1]) * h1);
      w.y = pk2(fsig(accr[mr][2]) * h2, fsig(accr[mr][3]) * h3);
      *(uint2*)(RHc + go) = w;                         // 4 bf16 rh, one b64
    }

    BARRIER();   // the ONLY barrier: rh visible, next-S staged; vmcnt survives

    // ---- pass 2 SWAPPED: acch += Uh^T-frag x rh-frag (reads identical) ----
    __builtin_amdgcn_s_setprio(1);
#pragma unroll
    for (int kb = 0; kb < 4; ++kb)
#pragma unroll
      for (int mr = 0; mr < 2; ++mr)
        acch[mr] = MFMA(W[5][kb], ldsA(RHc, mr, kb * 32), acch[mr], 0, 0, 0);
    __builtin_amdgcn_s_setprio(0);

    // ---- epilogue: h_t = hp + z*(hc - hp); ONE nontemporal f32x4 store ----
#pragma unroll
    for (int mr = 0; mr < 2; ++mr) {
      float hpf[4];
      hpf[0] = bf2f((ushort)(hpk[mr].x & 0xffff));
      hpf[1] = bf2f((ushort)(hpk[mr].x >> 16));
      hpf[2] = bf2f((ushort)(hpk[mr].y & 0xffff));
      hpf[3] = bf2f((ushort)(hpk[mr].y >> 16));
      f32x4 v;
#pragma unroll
      for (int j = 0; j < 4; ++j) {
        float hc = ftanh(acch[mr][j]);
        float zv = fsig(accz[mr][j]);
        v[j] = hpf[j] + zv * (hc - hpf[j]);
      }
      __builtin_nontemporal_store(
          v, (f32x4*)(out + (row0 + mr * 16 + l15) * 128 + n0 + q * 4));
    }
    // no trailing barrier: tri-buffered S / dbuf RH make it unnecessary
  }
}

extern "C" void kernel_launch(void* const* d_in, const int* in_sizes, int n_in,
                              void* d_out, int out_size, void* d_ws, size_t ws_size,
                              hipStream_t stream) {
  const float* x  = (const float*)d_in[0];
  const float* h  = (const float*)d_in[1];
  const float* Wz = (const float*)d_in[2];
  const float* Uz = (const float*)d_in[3];
  const float* bz = (const float*)d_in[4];
  const float* Wr = (const float*)d_in[5];
  const float* Ur = (const float*)d_in[6];
  const float* br = (const float*)d_in[7];
  const float* Wh = (const float*)d_in[8];
  const float* Uh = (const float*)d_in[9];
  const float* bh = (const float*)d_in[10];
  ushort* wt = (ushort*)d_ws;   // 98304 bf16 = 192 KB packed fragment order

  hipLaunchKernelGGL(wtrans_kernel, dim3(384), dim3(256), 0, stream,
                     Wz, Uz, Wr, Ur, Wh, Uh, wt);
  hipLaunchKernelGGL(gru_kernel, dim3(NBLK), dim3(512), 0, stream,
                     x, h, wt, bz, br, bh, (float*)d_out);
}

// Round 19
// 57.822 us; speedup vs baseline: 1.2749x; 1.0240x over previous
//
#include <hip/hip_runtime.h>
#include <hip/hip_bf16.h>

typedef __attribute__((ext_vector_type(8))) short bf16x8;
typedef __attribute__((ext_vector_type(4))) float f32x4;

#define GRU_B 131072
#define BM 32
#define TPB 8                        // row-tiles per persistent block
#define NBLK (GRU_B / (BM * TPB))    // 512 blocks

static __device__ __forceinline__ ushort f2bf(float f) {
  union { float f; unsigned u; } v; v.f = f;
  unsigned r = v.u + 0x7FFFu + ((v.u >> 16) & 1u);   // RNE
  return (ushort)(r >> 16);
}
static __device__ __forceinline__ float bf2f(ushort u) {
  union { unsigned u; float f; } v; v.u = ((unsigned)u) << 16;
  return v.f;
}
static __device__ __forceinline__ unsigned pk2(float a, float b) {
  float2 t; t.x = a; t.y = b;
  __hip_bfloat162 r = __float22bfloat162_rn(t);      // v_cvt_pk_bf16_f32
  union { __hip_bfloat162 b; unsigned u; } cv; cv.b = r;
  return cv.u;
}
static __device__ __forceinline__ float fsig(float x) {
  return __builtin_amdgcn_rcpf(1.0f + __expf(-x));
}
static __device__ __forceinline__ float ftanh(float x) {
  return 1.0f - 2.0f * __builtin_amdgcn_rcpf(1.0f + __expf(2.0f * x));
}
// two-bit XOR swizzle: b128 row reads 2-way (free), b64 row-gathers conflict-free
static __device__ __forceinline__ int swz(int row, int cbyte) {
  return (row * 256 + cbyte) ^ ((row & 7) << 4) ^ ((row & 8) << 2);
}

// Raw barrier: LDS visibility only — NO vmcnt drain, prefetch loads survive.
#define BARRIER() do {                                       \
  asm volatile("s_waitcnt lgkmcnt(0)" ::: "memory");         \
  __builtin_amdgcn_s_barrier();                              \
  asm volatile("" ::: "memory");                             \
} while (0)

// Pack six 128x128 fp32 weight matrices into per-lane MFMA fragment order:
// chunk = ((mat*8 + cb)*4 + kb), 1KB each; within chunk lane*16B holds
// w[kb*32 + (lane>>4)*8 + e][cb*16 + (lane&15)], e=0..7, bf16.
// Simultaneously a B-frag of W and an A-frag of W^T (lane-symmetric).
__global__ void wtrans_kernel(const float* __restrict__ wz, const float* __restrict__ uz,
                              const float* __restrict__ wr, const float* __restrict__ ur,
                              const float* __restrict__ wh, const float* __restrict__ uh,
                              ushort* __restrict__ outw) {
  int f = blockIdx.x * 256 + threadIdx.x;          // 0..98303 (coalesced write)
  int mat = f >> 14;
  int rem = f & 16383;
  int chunk = rem >> 9;                            // 0..31
  int lane = (rem >> 3) & 63;
  int e = rem & 7;
  int cb = chunk >> 2, k0b = chunk & 3;
  int n = cb * 16 + (lane & 15);
  int k = k0b * 32 + (lane >> 4) * 8 + e;
  const float* src = (mat == 0) ? wz : (mat == 1) ? uz : (mat == 2) ? wr
                   : (mat == 3) ? ur : (mat == 4) ? wh : uh;
  outw[f] = f2bf(src[k * 128 + n]);
}

#define MFMA __builtin_amdgcn_mfma_f32_16x16x32_bf16

__global__ __launch_bounds__(512, 2) void gru_kernel(
    const float* __restrict__ x, const float* __restrict__ hprev,
    const ushort* __restrict__ wt,
    const float* __restrict__ bz, const float* __restrict__ br,
    const float* __restrict__ bh, float* __restrict__ out) {
  // 64 KB: S[i]=i*16K (xs +0, hs +8K) tri-buffered; RH[r]=48K + r*8K dbuf
  __shared__ __align__(16) char smem[65536];

  const int tid = threadIdx.x;
  const int lane = tid & 63;
  const int wid = tid >> 6;          // 8 waves: 16 output cols each
  const int l15 = lane & 15;
  const int q = lane >> 4;
  const int n0 = wid * 16;

  // SWAPPED output layout: lane holds (batch row m = mtile*16+l15,
  // hidden cols n = n0 + q*4 + j, j=0..3). Bias varies along j:
  const float4 brv = *(const float4*)(br + n0 + q * 4);
  const float4 bzv = *(const float4*)(bz + n0 + q * 4);
  const float4 bhv = *(const float4*)(bh + n0 + q * 4);
  const f32x4 brv4 = {brv.x, brv.y, brv.z, brv.w};
  const f32x4 bzv4 = {bzv.x, bzv.y, bzv.z, bzv.w};
  const f32x4 bhv4 = {bhv.x, bhv.y, bhv.z, bhv.w};

  // hoist all 24 weight fragments into registers (reused across 8 tiles)
  const ushort* wlane = wt + (lane << 3);
  bf16x8 W[6][4];
#pragma unroll
  for (int mat = 0; mat < 6; ++mat)
#pragma unroll
    for (int kb = 0; kb < 4; ++kb)
      W[mat][kb] = *(const bf16x8*)(wlane + ((((mat << 3) + wid) << 2) + kb) * 512);

  auto ldsA = [&](const char* base, int mr, int k0) -> bf16x8 {
    int row = mr * 16 + l15;
    return *(const bf16x8*)(base + swz(row, (k0 + q * 8) * 2));
  };

  const long tile0 = (long)blockIdx.x * TPB;
  const f32x4* xg = (const f32x4*)x;
  const f32x4* hg = (const f32x4*)hprev;

  // staging offsets (lane-constant)
  const int r0 = tid >> 5, cb0 = (tid & 31) << 3;
  const int bo0 = swz(r0, cb0), bo1 = swz(r0 + 16, cb0);
  // rh/hp wide-op offsets: row = mr*16 + l15, byte col = (n0 + q*4)*2
  const int go0 = swz(l15, (n0 + q * 4) * 2);
  const int go1 = swz(16 + l15, (n0 + q * 4) * 2);

  auto stage = [&](char* S, const f32x4& a0, const f32x4& a1,
                   const f32x4& b0, const f32x4& b1) {
    uint2 v;
    v.x = pk2(a0.x, a0.y); v.y = pk2(a0.z, a0.w); *(uint2*)(S + bo0) = v;
    v.x = pk2(a1.x, a1.y); v.y = pk2(a1.z, a1.w); *(uint2*)(S + bo1) = v;
    v.x = pk2(b0.x, b0.y); v.y = pk2(b0.z, b0.w); *(uint2*)(S + 8192 + bo0) = v;
    v.x = pk2(b1.x, b1.y); v.y = pk2(b1.z, b1.w); *(uint2*)(S + 8192 + bo1) = v;
  };

  // -------- prologue: stage tile0, load tile1 regs (nontemporal LOADS only:
  //          streaming reads stay out of L2 so weight frags stay hot) --------
  f32x4 px0, px1, ph0, ph1;
  {
    long toff = tile0 * 1024;       // f32x4 index of tile 0
    px0 = __builtin_nontemporal_load(xg + toff + tid);
    px1 = __builtin_nontemporal_load(xg + toff + 512 + tid);
    ph0 = __builtin_nontemporal_load(hg + toff + tid);
    ph1 = __builtin_nontemporal_load(hg + toff + 512 + tid);
    stage(smem, px0, px1, ph0, ph1);
    if (TPB > 1) {
      toff += 1024;
      px0 = __builtin_nontemporal_load(xg + toff + tid);
      px1 = __builtin_nontemporal_load(xg + toff + 512 + tid);
      ph0 = __builtin_nontemporal_load(hg + toff + tid);
      ph1 = __builtin_nontemporal_load(hg + toff + 512 + tid);
    }
  }
  BARRIER();

  for (int t = 0; t < TPB; ++t) {
    char* Scur = smem + (t % 3) * 16384;
    char* RHc  = smem + 49152 + (t & 1) * 8192;
    const long row0 = (tile0 + t) * BM;

    // ---- stage tile t+1 from regs ----
    if (t + 1 < TPB) stage(smem + ((t + 1) % 3) * 16384, px0, px1, ph0, ph1);

    // ---- issue tile t+2 loads (raw barrier below won't drain them) ----
    if (t + 2 < TPB) {
      long toff = (tile0 + t + 2) * 1024;
      px0 = __builtin_nontemporal_load(xg + toff + tid);
      px1 = __builtin_nontemporal_load(xg + toff + 512 + tid);
      ph0 = __builtin_nontemporal_load(hg + toff + tid);
      ph1 = __builtin_nontemporal_load(hg + toff + 512 + tid);
    }

    // ---- pass 1 SWAPPED: accT = W^T-frag x act-frag (C^T layout out) ----
    //      accr = (x@Wr + h@Ur + br)^T ; accz ; acch = (x@Wh + bh)^T
    f32x4 accr[2], accz[2], acch[2];
    accr[0] = brv4; accr[1] = brv4;
    accz[0] = bzv4; accz[1] = bzv4;
    acch[0] = bhv4; acch[1] = bhv4;
    __builtin_amdgcn_s_setprio(1);
#pragma unroll
    for (int kb = 0; kb < 4; ++kb)
#pragma unroll
      for (int mr = 0; mr < 2; ++mr) {
        bf16x8 ax = ldsA(Scur, mr, kb * 32);
        bf16x8 ah = ldsA(Scur + 8192, mr, kb * 32);
        accr[mr] = MFMA(W[2][kb], ax, accr[mr], 0, 0, 0);
        accr[mr] = MFMA(W[3][kb], ah, accr[mr], 0, 0, 0);
        accz[mr] = MFMA(W[0][kb], ax, accz[mr], 0, 0, 0);
        accz[mr] = MFMA(W[1][kb], ah, accz[mr], 0, 0, 0);
        acch[mr] = MFMA(W[4][kb], ax, acch[mr], 0, 0, 0);
      }
    __builtin_amdgcn_s_setprio(0);

    // ---- rh = sigmoid(accr)*hp -> RH, WIDE ops (b64), hp cached ----
    uint2 hpk[2];
#pragma unroll
    for (int mr = 0; mr < 2; ++mr) {
      int go = mr ? go1 : go0;
      uint2 hp4 = *(const uint2*)(Scur + 8192 + go);   // 4 bf16 hp
      hpk[mr] = hp4;
      float h0 = bf2f((ushort)(hp4.x & 0xffff)), h1 = bf2f((ushort)(hp4.x >> 16));
      float h2 = bf2f((ushort)(hp4.y & 0xffff)), h3 = bf2f((ushort)(hp4.y >> 16));
      uint2 w;
      w.x = pk2(fsig(accr[mr][0]) * h0, fsig(accr[mr][1]) * h1);
      w.y = pk2(fsig(accr[mr][2]) * h2, fsig(accr[mr][3]) * h3);
      *(uint2*)(RHc + go) = w;                         // 4 bf16 rh, one b64
    }

    BARRIER();   // the ONLY barrier: rh visible, next-S staged; vmcnt survives

    // ---- pass 2 SWAPPED: acch += Uh^T-frag x rh-frag (reads identical) ----
    __builtin_amdgcn_s_setprio(1);
#pragma unroll
    for (int kb = 0; kb < 4; ++kb)
#pragma unroll
      for (int mr = 0; mr < 2; ++mr)
        acch[mr] = MFMA(W[5][kb], ldsA(RHc, mr, kb * 32), acch[mr], 0, 0, 0);
    __builtin_amdgcn_s_setprio(0);

    // ---- epilogue: h_t = hp + z*(hc - hp); ONE regular f32x4 store ----
    //      (nt stores write through L2 -> WRITE_SIZE 65.5->89.5 MB in r18;
    //       regular stores coalesce to full lines in L2)
#pragma unroll
    for (int mr = 0; mr < 2; ++mr) {
      float hpf[4];
      hpf[0] = bf2f((ushort)(hpk[mr].x & 0xffff));
      hpf[1] = bf2f((ushort)(hpk[mr].x >> 16));
      hpf[2] = bf2f((ushort)(hpk[mr].y & 0xffff));
      hpf[3] = bf2f((ushort)(hpk[mr].y >> 16));
      f32x4 v;
#pragma unroll
      for (int j = 0; j < 4; ++j) {
        float hc = ftanh(acch[mr][j]);
        float zv = fsig(accz[mr][j]);
        v[j] = hpf[j] + zv * (hc - hpf[j]);
      }
      *(f32x4*)(out + (row0 + mr * 16 + l15) * 128 + n0 + q * 4) = v;
    }
    // no trailing barrier: tri-buffered S / dbuf RH make it unnecessary
  }
}

extern "C" void kernel_launch(void* const* d_in, const int* in_sizes, int n_in,
                              void* d_out, int out_size, void* d_ws, size_t ws_size,
                              hipStream_t stream) {
  const float* x  = (const float*)d_in[0];
  const float* h  = (const float*)d_in[1];
  const float* Wz = (const float*)d_in[2];
  const float* Uz = (const float*)d_in[3];
  const float* bz = (const float*)d_in[4];
  const float* Wr = (const float*)d_in[5];
  const float* Ur = (const float*)d_in[6];
  const float* br = (const float*)d_in[7];
  const float* Wh = (const float*)d_in[8];
  const float* Uh = (const float*)d_in[9];
  const float* bh = (const float*)d_in[10];
  ushort* wt = (ushort*)d_ws;   // 98304 bf16 = 192 KB packed fragment order

  hipLaunchKernelGGL(wtrans_kernel, dim3(384), dim3(256), 0, stream,
                     Wz, Uz, Wr, Ur, Wh, Uh, wt);
  hipLaunchKernelGGL(gru_kernel, dim3(NBLK), dim3(512), 0, stream,
                     x, h, wt, bz, br, bh, (float*)d_out);
}

// Round 20
// 53.451 us; speedup vs baseline: 1.3792x; 1.0818x over previous
//
#include <hip/hip_runtime.h>
#include <hip/hip_bf16.h>

typedef __attribute__((ext_vector_type(8))) short bf16x8;
typedef __attribute__((ext_vector_type(4))) float f32x4;

#define GRU_B 131072
#define BM 32
#define TPB 8                        // row-tiles per persistent block
#define NBLK (GRU_B / (BM * TPB))    // 512 blocks

static __device__ __forceinline__ ushort f2bf(float f) {
  union { float f; unsigned u; } v; v.f = f;
  unsigned r = v.u + 0x7FFFu + ((v.u >> 16) & 1u);   // RNE
  return (ushort)(r >> 16);
}
static __device__ __forceinline__ float bf2f(ushort u) {
  union { unsigned u; float f; } v; v.u = ((unsigned)u) << 16;
  return v.f;
}
static __device__ __forceinline__ unsigned pk2(float a, float b) {
  float2 t; t.x = a; t.y = b;
  __hip_bfloat162 r = __float22bfloat162_rn(t);      // v_cvt_pk_bf16_f32
  union { __hip_bfloat162 b; unsigned u; } cv; cv.b = r;
  return cv.u;
}
static __device__ __forceinline__ float fsig(float x) {
  return __builtin_amdgcn_rcpf(1.0f + __expf(-x));
}
static __device__ __forceinline__ float ftanh(float x) {
  return 1.0f - 2.0f * __builtin_amdgcn_rcpf(1.0f + __expf(2.0f * x));
}
// two-bit XOR swizzle: b128 row reads 2-way (free), b64 row-gathers conflict-free
static __device__ __forceinline__ int swz(int row, int cbyte) {
  return (row * 256 + cbyte) ^ ((row & 7) << 4) ^ ((row & 8) << 2);
}

// Raw barrier: LDS visibility only — NO vmcnt drain, prefetch loads survive.
#define BARRIER() do {                                       \
  asm volatile("s_waitcnt lgkmcnt(0)" ::: "memory");         \
  __builtin_amdgcn_s_barrier();                              \
  asm volatile("" ::: "memory");                             \
} while (0)

// Pack six 128x128 fp32 weight matrices into per-lane MFMA fragment order:
// chunk = ((mat*8 + cb)*4 + kb), 1KB each; within chunk lane*16B holds
// w[kb*32 + (lane>>4)*8 + e][cb*16 + (lane&15)], e=0..7, bf16.
// Simultaneously a B-frag of W and an A-frag of W^T (lane-symmetric).
__global__ void wtrans_kernel(const float* __restrict__ wz, const float* __restrict__ uz,
                              const float* __restrict__ wr, const float* __restrict__ ur,
                              const float* __restrict__ wh, const float* __restrict__ uh,
                              ushort* __restrict__ outw) {
  int f = blockIdx.x * 256 + threadIdx.x;          // 0..98303 (coalesced write)
  int mat = f >> 14;
  int rem = f & 16383;
  int chunk = rem >> 9;                            // 0..31
  int lane = (rem >> 3) & 63;
  int e = rem & 7;
  int cb = chunk >> 2, k0b = chunk & 3;
  int n = cb * 16 + (lane & 15);
  int k = k0b * 32 + (lane >> 4) * 8 + e;
  const float* src = (mat == 0) ? wz : (mat == 1) ? uz : (mat == 2) ? wr
                   : (mat == 3) ? ur : (mat == 4) ? wh : uh;
  outw[f] = f2bf(src[k * 128 + n]);
}

#define MFMA __builtin_amdgcn_mfma_f32_16x16x32_bf16

__global__ __launch_bounds__(512, 2) void gru_kernel(
    const float* __restrict__ x, const float* __restrict__ hprev,
    const ushort* __restrict__ wt,
    const float* __restrict__ bz, const float* __restrict__ br,
    const float* __restrict__ bh, float* __restrict__ out) {
  // 64 KB: S[i]=i*16K (xs +0, hs +8K) tri-buffered; RH[r]=48K + r*8K dbuf
  __shared__ __align__(16) char smem[65536];

  const int tid = threadIdx.x;
  const int lane = tid & 63;
  const int wid = tid >> 6;          // 8 waves: 16 output cols each
  const int l15 = lane & 15;
  const int q = lane >> 4;
  const int n0 = wid * 16;

  // SWAPPED output layout: lane holds (batch row m = mtile*16+l15,
  // hidden cols n = n0 + q*4 + j, j=0..3). Bias varies along j:
  const float4 brv = *(const float4*)(br + n0 + q * 4);
  const float4 bzv = *(const float4*)(bz + n0 + q * 4);
  const float4 bhv = *(const float4*)(bh + n0 + q * 4);
  const f32x4 brv4 = {brv.x, brv.y, brv.z, brv.w};
  const f32x4 bzv4 = {bzv.x, bzv.y, bzv.z, bzv.w};
  const f32x4 bhv4 = {bhv.x, bhv.y, bhv.z, bhv.w};

  // hoist all 24 weight fragments into registers (reused across 8 tiles)
  const ushort* wlane = wt + (lane << 3);
  bf16x8 W[6][4];
#pragma unroll
  for (int mat = 0; mat < 6; ++mat)
#pragma unroll
    for (int kb = 0; kb < 4; ++kb)
      W[mat][kb] = *(const bf16x8*)(wlane + ((((mat << 3) + wid) << 2) + kb) * 512);

  auto ldsA = [&](const char* base, int mr, int k0) -> bf16x8 {
    int row = mr * 16 + l15;
    return *(const bf16x8*)(base + swz(row, (k0 + q * 8) * 2));
  };

  const long tile0 = (long)blockIdx.x * TPB;
  const f32x4* xg = (const f32x4*)x;
  const f32x4* hg = (const f32x4*)hprev;

  // staging offsets (lane-constant)
  const int r0 = tid >> 5, cb0 = (tid & 31) << 3;
  const int bo0 = swz(r0, cb0), bo1 = swz(r0 + 16, cb0);
  // rh/hp wide-op offsets: row = mr*16 + l15, byte col = (n0 + q*4)*2
  const int go0 = swz(l15, (n0 + q * 4) * 2);
  const int go1 = swz(16 + l15, (n0 + q * 4) * 2);

  auto stage = [&](char* S, const f32x4& a0, const f32x4& a1,
                   const f32x4& b0, const f32x4& b1) {
    uint2 v;
    v.x = pk2(a0.x, a0.y); v.y = pk2(a0.z, a0.w); *(uint2*)(S + bo0) = v;
    v.x = pk2(a1.x, a1.y); v.y = pk2(a1.z, a1.w); *(uint2*)(S + bo1) = v;
    v.x = pk2(b0.x, b0.y); v.y = pk2(b0.z, b0.w); *(uint2*)(S + 8192 + bo0) = v;
    v.x = pk2(b1.x, b1.y); v.y = pk2(b1.z, b1.w); *(uint2*)(S + 8192 + bo1) = v;
  };

  // -------- prologue: stage tile0, load tile1 regs (REGULAR loads: L3 must
  //          cache the x/h stream — r19 showed nt loads defeat replay L3-hits)
  f32x4 px0, px1, ph0, ph1;
  {
    long toff = tile0 * 1024;       // f32x4 index of tile 0
    px0 = xg[toff + tid]; px1 = xg[toff + 512 + tid];
    ph0 = hg[toff + tid]; ph1 = hg[toff + 512 + tid];
    stage(smem, px0, px1, ph0, ph1);
    if (TPB > 1) {
      toff += 1024;
      px0 = xg[toff + tid]; px1 = xg[toff + 512 + tid];
      ph0 = hg[toff + tid]; ph1 = hg[toff + 512 + tid];
    }
  }
  BARRIER();

  for (int t = 0; t < TPB; ++t) {
    char* Scur = smem + (t % 3) * 16384;
    char* RHc  = smem + 49152 + (t & 1) * 8192;
    const long row0 = (tile0 + t) * BM;

    // ---- stage tile t+1 from regs ----
    if (t + 1 < TPB) stage(smem + ((t + 1) % 3) * 16384, px0, px1, ph0, ph1);

    // ---- issue tile t+2 loads (raw barrier below won't drain them) ----
    if (t + 2 < TPB) {
      long toff = (tile0 + t + 2) * 1024;
      px0 = xg[toff + tid]; px1 = xg[toff + 512 + tid];
      ph0 = hg[toff + tid]; ph1 = hg[toff + 512 + tid];
    }

    // ---- pass 1 SWAPPED: accT = W^T-frag x act-frag (C^T layout out) ----
    //      accr = (x@Wr + h@Ur + br)^T ; accz ; acch = (x@Wh + bh)^T
    f32x4 accr[2], accz[2], acch[2];
    accr[0] = brv4; accr[1] = brv4;
    accz[0] = bzv4; accz[1] = bzv4;
    acch[0] = bhv4; acch[1] = bhv4;
    __builtin_amdgcn_s_setprio(1);
#pragma unroll
    for (int kb = 0; kb < 4; ++kb)
#pragma unroll
      for (int mr = 0; mr < 2; ++mr) {
        bf16x8 ax = ldsA(Scur, mr, kb * 32);
        bf16x8 ah = ldsA(Scur + 8192, mr, kb * 32);
        accr[mr] = MFMA(W[2][kb], ax, accr[mr], 0, 0, 0);
        accr[mr] = MFMA(W[3][kb], ah, accr[mr], 0, 0, 0);
        accz[mr] = MFMA(W[0][kb], ax, accz[mr], 0, 0, 0);
        accz[mr] = MFMA(W[1][kb], ah, accz[mr], 0, 0, 0);
        acch[mr] = MFMA(W[4][kb], ax, acch[mr], 0, 0, 0);
      }
    __builtin_amdgcn_s_setprio(0);

    // ---- rh = sigmoid(accr)*hp -> RH, WIDE ops (b64), hp cached ----
    uint2 hpk[2];
#pragma unroll
    for (int mr = 0; mr < 2; ++mr) {
      int go = mr ? go1 : go0;
      uint2 hp4 = *(const uint2*)(Scur + 8192 + go);   // 4 bf16 hp
      hpk[mr] = hp4;
      float h0 = bf2f((ushort)(hp4.x & 0xffff)), h1 = bf2f((ushort)(hp4.x >> 16));
      float h2 = bf2f((ushort)(hp4.y & 0xffff)), h3 = bf2f((ushort)(hp4.y >> 16));
      uint2 w;
      w.x = pk2(fsig(accr[mr][0]) * h0, fsig(accr[mr][1]) * h1);
      w.y = pk2(fsig(accr[mr][2]) * h2, fsig(accr[mr][3]) * h3);
      *(uint2*)(RHc + go) = w;                         // 4 bf16 rh, one b64
    }

    BARRIER();   // the ONLY barrier: rh visible, next-S staged; vmcnt survives

    // ---- pass 2 SWAPPED: acch += Uh^T-frag x rh-frag (reads identical) ----
    __builtin_amdgcn_s_setprio(1);
#pragma unroll
    for (int kb = 0; kb < 4; ++kb)
#pragma unroll
      for (int mr = 0; mr < 2; ++mr)
        acch[mr] = MFMA(W[5][kb], ldsA(RHc, mr, kb * 32), acch[mr], 0, 0, 0);
    __builtin_amdgcn_s_setprio(0);

    // ---- epilogue: h_t = hp + z*(hc - hp); ONE regular f32x4 store per mr ----
#pragma unroll
    for (int mr = 0; mr < 2; ++mr) {
      float hpf[4];
      hpf[0] = bf2f((ushort)(hpk[mr].x & 0xffff));
      hpf[1] = bf2f((ushort)(hpk[mr].x >> 16));
      hpf[2] = bf2f((ushort)(hpk[mr].y & 0xffff));
      hpf[3] = bf2f((ushort)(hpk[mr].y >> 16));
      f32x4 v;
#pragma unroll
      for (int j = 0; j < 4; ++j) {
        float hc = ftanh(acch[mr][j]);
        float zv = fsig(accz[mr][j]);
        v[j] = hpf[j] + zv * (hc - hpf[j]);
      }
      *(f32x4*)(out + (row0 + mr * 16 + l15) * 128 + n0 + q * 4) = v;
    }
    // no trailing barrier: tri-buffered S / dbuf RH make it unnecessary
  }
}

extern "C" void kernel_launch(void* const* d_in, const int* in_sizes, int n_in,
                              void* d_out, int out_size, void* d_ws, size_t ws_size,
                              hipStream_t stream) {
  const float* x  = (const float*)d_in[0];
  const float* h  = (const float*)d_in[1];
  const float* Wz = (const float*)d_in[2];
  const float* Uz = (const float*)d_in[3];
  const float* bz = (const float*)d_in[4];
  const float* Wr = (const float*)d_in[5];
  const float* Ur = (const float*)d_in[6];
  const float* br = (const float*)d_in[7];
  const float* Wh = (const float*)d_in[8];
  const float* Uh = (const float*)d_in[9];
  const float* bh = (const float*)d_in[10];
  ushort* wt = (ushort*)d_ws;   // 98304 bf16 = 192 KB packed fragment order

  hipLaunchKernelGGL(wtrans_kernel, dim3(384), dim3(256), 0, stream,
                     Wz, Uz, Wr, Ur, Wh, Uh, wt);
  hipLaunchKernelGGL(gru_kernel, dim3(NBLK), dim3(512), 0, stream,
                     x, h, wt, bz, br, bh, (float*)d_out);
}